// Round 11
// baseline (122.081 us; speedup 1.0000x reference)
//
#include <hip/hip_runtime.h>
#include <hip/hip_bf16.h>
#include <math.h>

// PAM fused attention, round 11: 4-way intra-block key split -> 4 blocks/CU,
// 4 waves/SIMD (2x R10) with zero exp duplication. R5 showed wave-scaling
// works on this loop; R10 dedup'd the work; this round combines both.
// VGPR squeezed <=128 (no K/V shadow regs; direct 1-ahead loads).
// B=4, Cm=6, C=64, N=4096.

#define BATCH 4
#define CMAP  6
#define CH    64
#define NSP   4096
#define TN    64         // keys per tile
#define NTW   16         // tiles per wave (1024 keys per key-quarter)
#define PSTR  72         // p_scr row stride (bf16)

typedef __attribute__((ext_vector_type(8))) short short8;
typedef __attribute__((ext_vector_type(4))) float f32x4;

#if __has_builtin(__builtin_amdgcn_exp2f)
#define EXP2(x) __builtin_amdgcn_exp2f(x)
#else
#define EXP2(x) exp2f(x)
#endif

__device__ __forceinline__ unsigned f2bf(float f) {      // RNE f32->bf16 bits
    unsigned u = __float_as_uint(f);
    return (u + 0x7fffu + ((u >> 16) & 1u)) >> 16;
}

#define INVLN2 1.44269504088896f
#define SHIFT_BF16 0xC238u   /* bf16(-46.0): fixed softmax shift (exact, cancels) */
#define ONE_BF16   0x3F80u

// V fragment layout: featdf[b][ht(128)][cb(4)][512]
//   half-tile ht = 32 keys; cb = 16-channel block.
//   elem ((quad*16 + r)*8 + j) = V[m=ht*32+quad*8+j][ch=cb*16+r]
//   -> MFMA lane l=(quad*16+row16) loads its 16B at frag_base + l*8 elems.

// ---------------- kernel 1: projections + V fragment transpose ----------------
// (unchanged from R7-R10, verified) grid (NSP/64, 2, BATCH), block 256.
__global__ void proj_kernel(const float* __restrict__ map1, const float* __restrict__ map2,
                            const float* __restrict__ fm,
                            const float* __restrict__ wb, const float* __restrict__ bb,
                            const float* __restrict__ wc, const float* __restrict__ bc,
                            const float* __restrict__ wd, const float* __restrict__ bd,
                            unsigned short* __restrict__ featq8,
                            unsigned short* __restrict__ featk8,
                            unsigned short* __restrict__ featdf)
{
    __shared__ unsigned short vfrag[2048];   // [ht(2)][cb_local(2)][512] = 4KB

    const int b    = blockIdx.z;
    const int half = blockIdx.y;
    const int lane = threadIdx.x & 63;
    const int og   = threadIdx.x >> 6;
    const int n    = blockIdx.x * 64 + lane;

    const int ht = lane >> 5;
    const int mm = lane & 31;
    const int q4 = mm >> 3, jj = mm & 7;
    const int cb_local = og >> 1;
    float vals[CH];
#pragma unroll
    for (int c = 0; c < CH; ++c)
        vals[c] = fm[(size_t)(b*CH + c)*NSP + n];
#pragma unroll
    for (int oi = 0; oi < 8; ++oi) {
        const int o = half*32 + og*8 + oi;
        float a = bd[o];
#pragma unroll
        for (int c = 0; c < CH; ++c)
            a = fmaf(vals[c], wd[o*CH + c], a);
        const int r = (og & 1)*8 + oi;
        vfrag[(ht*2 + cb_local)*512 + (q4*16 + r)*8 + jj] = (unsigned short)f2bf(a);
    }

    if (half == 0 && og == 0) {
        float v1[CMAP], v2[CMAP];
#pragma unroll
        for (int c = 0; c < CMAP; ++c) {
            v1[c] = map1[(size_t)(b*CMAP + c)*NSP + n];
            v2[c] = map2[(size_t)(b*CMAP + c)*NSP + n];
        }
        unsigned qv[CMAP], kv[CMAP];
#pragma unroll
        for (int o = 0; o < CMAP; ++o) {
            float a1 = bb[o], a2 = bc[o];
#pragma unroll
            for (int c = 0; c < CMAP; ++c) {
                a1 = fmaf(v1[c], wb[o*CMAP + c], a1);
                a2 = fmaf(v2[c], wc[o*CMAP + c], a2);
            }
            qv[o] = f2bf(a1 * INVLN2);
            kv[o] = f2bf(a2);
        }
        uint4 qw, kw;
        qw.x = qv[0] | (qv[1] << 16);
        qw.y = qv[2] | (qv[3] << 16);
        qw.z = qv[4] | (qv[5] << 16);
        qw.w = SHIFT_BF16;
        kw.x = kv[0] | (kv[1] << 16);
        kw.y = kv[2] | (kv[3] << 16);
        kw.z = kv[4] | (kv[5] << 16);
        kw.w = ONE_BF16;
        *(uint4*)&featq8[(size_t)(b*NSP + n)*8] = qw;
        *(uint4*)&featk8[(size_t)(b*NSP + n)*8] = kw;
    }

    __syncthreads();

    {
        const int tt = threadIdx.x;
        const uint4 d = *(const uint4*)&vfrag[tt*8];
        const int ht2 = tt >> 7, inner = tt & 127;
        const size_t off = (((size_t)(b*128 + blockIdx.x*2 + ht2)*4) + half*2)*512
                         + (size_t)inner*8;
        *(uint4*)&featdf[off] = d;
    }
}

// ---------------- kernel 2: attention, 4-way intra-block key split -----------
// grid (NSP/16=256, BATCH) = 1024 blocks -> 4 blocks/CU, 16 waves/CU.
// Wave w: 16 queries x 64 channels x keys [w*1024, +1024). LDS ~33 KB/block.
__global__ __launch_bounds__(256, 4)
void attn_kernel(const unsigned short* __restrict__ featq8,
                 const unsigned short* __restrict__ featk8,
                 const unsigned short* __restrict__ featdf,
                 const float* __restrict__ fm, const float* __restrict__ alpha_p,
                 float* __restrict__ out)
{
    __shared__ unsigned short p_scr[2][4][16*PSTR];  // [buf][wave][q][m] wave-private
    __shared__ float cmb[3][64][20];                 // key-quarter partial exchange

    const int b    = blockIdx.y;
    const int t    = threadIdx.x;
    const int lane = t & 63, w = t >> 6;           // w = key quarter
    const int row16 = lane & 15, quad = lane >> 4;
    const int n0   = blockIdx.x * 16;              // block's 16 queries
    const int m0   = w * (NSP/4);                  // wave's 1024 keys

    // Q B-frag: B[k=quad*8+j][q=row16]; quads 1-3 zero (kills unguarded-K garbage)
    short8 qf = {0,0,0,0,0,0,0,0};
    if (quad == 0)
        qf = *(const short8*)&featq8[(size_t)(b*NSP + n0 + row16)*8];

    // ones B-frag: accL = P x 1 -> softmax denominator, same D q-mapping as acc
    const short8 onesb = {(short)ONE_BF16,(short)ONE_BF16,(short)ONE_BF16,(short)ONE_BF16,
                          (short)ONE_BF16,(short)ONE_BF16,(short)ONE_BF16,(short)ONE_BF16};

    // K A-frag stream (this key quarter)
    const unsigned short* kbase = featk8 + ((size_t)(b*NSP + m0) + row16)*8 + quad*8;
    // V fragment stream: coalesced, lane*16B within each 1KB frag; all 4 cb
    const unsigned short* vfb = featdf + ((size_t)b*128*4)*512 + lane*8;
    const int hb = w * 32;                         // half-tile base for this quarter

    const f32x4 zf = {0.f,0.f,0.f,0.f};
    f32x4 acc[4] = {zf, zf, zf, zf};
    f32x4 accL = zf;
    const int prow = row16 * PSTR;

#define PAM_DO(pwp, mb, sv)                                                     \
    {                                                                           \
        const float p0 = EXP2(sv[0]), p1 = EXP2(sv[1]);                         \
        const float p2 = EXP2(sv[2]), p3 = EXP2(sv[3]);                         \
        uint2 pp;                                                               \
        pp.x = __builtin_amdgcn_perm(__float_as_uint(p1), __float_as_uint(p0), 0x07060302u); \
        pp.y = __builtin_amdgcn_perm(__float_as_uint(p3), __float_as_uint(p2), 0x07060302u); \
        *(uint2*)((pwp) + (mb)*16) = pp;                                        \
    }

#define LOADK(mt)                                                               \
    kc0 = *(const short8*)(kbase + ((mt)*TN +  0)*8);                           \
    kc1 = *(const short8*)(kbase + ((mt)*TN + 16)*8);                           \
    kc2 = *(const short8*)(kbase + ((mt)*TN + 32)*8);                           \
    kc3 = *(const short8*)(kbase + ((mt)*TN + 48)*8);

    // V for tile vt: half-tiles hb+vt*2, hb+vt*2+1; cb 0..3 (8 x b128)
#define LOADV(vt)                                                               \
    vv0 = *(const short8*)(vfb + (size_t)((hb + (vt)*2 + 0)*4 + 0)*512);        \
    vv1 = *(const short8*)(vfb + (size_t)((hb + (vt)*2 + 1)*4 + 0)*512);        \
    vv2 = *(const short8*)(vfb + (size_t)((hb + (vt)*2 + 0)*4 + 1)*512);        \
    vv3 = *(const short8*)(vfb + (size_t)((hb + (vt)*2 + 1)*4 + 1)*512);        \
    vv4 = *(const short8*)(vfb + (size_t)((hb + (vt)*2 + 0)*4 + 2)*512);        \
    vv5 = *(const short8*)(vfb + (size_t)((hb + (vt)*2 + 1)*4 + 2)*512);        \
    vv6 = *(const short8*)(vfb + (size_t)((hb + (vt)*2 + 1)*4 + 3)*512);        \
    vv7 = *(const short8*)(vfb + (size_t)((hb + (vt)*2 + 0)*4 + 3)*512);

#define PV(a0_, a1_)                                                            \
    acc[0] = __builtin_amdgcn_mfma_f32_16x16x32_bf16(a0_, vv0, acc[0], 0, 0, 0); \
    acc[0] = __builtin_amdgcn_mfma_f32_16x16x32_bf16(a1_, vv1, acc[0], 0, 0, 0); \
    acc[1] = __builtin_amdgcn_mfma_f32_16x16x32_bf16(a0_, vv2, acc[1], 0, 0, 0); \
    acc[1] = __builtin_amdgcn_mfma_f32_16x16x32_bf16(a1_, vv3, acc[1], 0, 0, 0); \
    acc[2] = __builtin_amdgcn_mfma_f32_16x16x32_bf16(a0_, vv4, acc[2], 0, 0, 0); \
    acc[2] = __builtin_amdgcn_mfma_f32_16x16x32_bf16(a1_, vv5, acc[2], 0, 0, 0); \
    acc[3] = __builtin_amdgcn_mfma_f32_16x16x32_bf16(a0_, vv7, acc[3], 0, 0, 0); \
    acc[3] = __builtin_amdgcn_mfma_f32_16x16x32_bf16(a1_, vv6, acc[3], 0, 0, 0); \
    accL   = __builtin_amdgcn_mfma_f32_16x16x32_bf16(a0_, onesb, accL, 0, 0, 0); \
    accL   = __builtin_amdgcn_mfma_f32_16x16x32_bf16(a1_, onesb, accL, 0, 0, 0);

    short8 kc0, kc1, kc2, kc3;
    short8 vv0, vv1, vv2, vv3, vv4, vv5, vv6, vv7;
    f32x4 sp0, sp1, sp2, sp3;

    // ---------------- prologue ----------------
    LOADK(0)
    {   // i=0: scores(0) -> pack P(0) into buf[0]
        f32x4 a0 = __builtin_amdgcn_mfma_f32_16x16x32_bf16(kc0, qf, zf, 0, 0, 0);
        f32x4 a1 = __builtin_amdgcn_mfma_f32_16x16x32_bf16(kc1, qf, zf, 0, 0, 0);
        f32x4 a2 = __builtin_amdgcn_mfma_f32_16x16x32_bf16(kc2, qf, zf, 0, 0, 0);
        f32x4 a3 = __builtin_amdgcn_mfma_f32_16x16x32_bf16(kc3, qf, zf, 0, 0, 0);
        LOADK(1)
        unsigned short* pw = &p_scr[0][w][prow + quad*4];
        PAM_DO(pw, 0, a0) PAM_DO(pw, 1, a1) PAM_DO(pw, 2, a2) PAM_DO(pw, 3, a3)
    }
    // i=1: scores(1) -> s_prev regs
    sp0 = __builtin_amdgcn_mfma_f32_16x16x32_bf16(kc0, qf, zf, 0, 0, 0);
    sp1 = __builtin_amdgcn_mfma_f32_16x16x32_bf16(kc1, qf, zf, 0, 0, 0);
    sp2 = __builtin_amdgcn_mfma_f32_16x16x32_bf16(kc2, qf, zf, 0, 0, 0);
    sp3 = __builtin_amdgcn_mfma_f32_16x16x32_bf16(kc3, qf, zf, 0, 0, 0);
    LOADK(2)
    LOADV(0)                // V(0), used by PV(0) at i=2

    // ---------------- main loop: i = 2..15 ----------------
    // scores(i) || exp/pack/write P(i-1) || PV(i-2); K/V loaded 1 iter ahead
#pragma unroll 2
    for (int i = 2; i < NTW; ++i) {
        const f32x4 t0 = __builtin_amdgcn_mfma_f32_16x16x32_bf16(kc0, qf, zf, 0, 0, 0);
        const f32x4 t1 = __builtin_amdgcn_mfma_f32_16x16x32_bf16(kc1, qf, zf, 0, 0, 0);
        const f32x4 t2 = __builtin_amdgcn_mfma_f32_16x16x32_bf16(kc2, qf, zf, 0, 0, 0);
        const f32x4 t3 = __builtin_amdgcn_mfma_f32_16x16x32_bf16(kc3, qf, zf, 0, 0, 0);

        // reload K for next iter (i=15 reads past this quarter -> mapped ws,
        // values never consumed)
        LOADK(i + 1)

        // ds_read P(i-2) from buf[i&1] (written iter i-1)
        const unsigned short* pr = &p_scr[i & 1][w][prow + quad*8];
        const short8 a0 = *(const short8*)pr;          // m 0..31
        const short8 a1 = *(const short8*)(pr + 32);   // m 32..63

        // exp/pack/write P(i-1) -> buf[(i+1)&1]
        {
            unsigned short* pw = &p_scr[(i + 1) & 1][w][prow + quad*4];
            PAM_DO(pw, 0, sp0) PAM_DO(pw, 1, sp1) PAM_DO(pw, 2, sp2) PAM_DO(pw, 3, sp3)
        }

        // PV(i-2) with vv = V(i-2); l rides the MFMA pipe
        PV(a0, a1)

        // load V(i-1) for next iter's PV
        LOADV(i - 1)

        sp0 = t0; sp1 = t1; sp2 = t2; sp3 = t3;
    }

    // ---------------- epilogue ----------------
    {   // E1: PV(14) + write P(15)
        const unsigned short* pr = &p_scr[0][w][prow + quad*8];   // P(14): buf[16&1]
        const short8 a0 = *(const short8*)pr;
        const short8 a1 = *(const short8*)(pr + 32);
        unsigned short* pw = &p_scr[1][w][prow + quad*4];         // P(15) -> buf[1]
        PAM_DO(pw, 0, sp0) PAM_DO(pw, 1, sp1) PAM_DO(pw, 2, sp2) PAM_DO(pw, 3, sp3)
        PV(a0, a1)
        LOADV(15)                                                 // V(15)
    }
    {   // E2: PV(15)
        const unsigned short* pr = &p_scr[1][w][prow + quad*8];
        const short8 a0 = *(const short8*)pr;
        const short8 a1 = *(const short8*)(pr + 32);
        PV(a0, a1)
    }
#undef PAM_DO
#undef LOADK
#undef LOADV
#undef PV

    // ---------------- combine key quarters + epilogue ----------------
    if (w != 0) {
        float* c = cmb[w - 1][lane];
#pragma unroll
        for (int cb = 0; cb < 4; ++cb)
            *(float4*)&c[cb*4] = (float4){acc[cb][0], acc[cb][1], acc[cb][2], acc[cb][3]};
        *(float4*)&c[16] = (float4){accL[0], accL[1], accL[2], accL[3]};
    }
    __syncthreads();
    if (w == 0) {
#pragma unroll
        for (int ww = 0; ww < 3; ++ww) {
            const float* c = cmb[ww][lane];
#pragma unroll
            for (int cb = 0; cb < 4; ++cb) {
                const float4 po = *(const float4*)&c[cb*4];
                acc[cb][0] += po.x; acc[cb][1] += po.y;
                acc[cb][2] += po.z; acc[cb][3] += po.w;
            }
            const float4 lo = *(const float4*)&c[16];
            accL[0] += lo.x; accL[1] += lo.y; accL[2] += lo.z; accL[3] += lo.w;
        }
        const float alpha = alpha_p[0];
        const float c0 = alpha / (accL[0] + 1e-30f);
        const float c1 = alpha / (accL[1] + 1e-30f);
        const float c2 = alpha / (accL[2] + 1e-30f);
        const float c3 = alpha / (accL[3] + 1e-30f);
#pragma unroll
        for (int cb = 0; cb < 4; ++cb) {
            const int ch = cb*16 + row16;
            const size_t base = (size_t)(b*CH + ch)*NSP + n0 + quad*4;
            const float4 f = *(const float4*)&fm[base];
            float4 o;
            o.x = fmaf(c0, acc[cb][0], f.x);
            o.y = fmaf(c1, acc[cb][1], f.y);
            o.z = fmaf(c2, acc[cb][2], f.z);
            o.w = fmaf(c3, acc[cb][3], f.w);
            *(float4*)&out[base] = o;
        }
    }
}

// ---------------- launcher ----------------
extern "C" void kernel_launch(void* const* d_in, const int* in_sizes, int n_in,
                              void* d_out, int out_size, void* d_ws, size_t ws_size,
                              hipStream_t stream)
{
    const float* map1  = (const float*)d_in[0];
    const float* map2  = (const float*)d_in[1];
    const float* fm    = (const float*)d_in[2];
    const float* wb    = (const float*)d_in[3];
    const float* bb    = (const float*)d_in[4];
    const float* wc    = (const float*)d_in[5];
    const float* bc    = (const float*)d_in[6];
    const float* wd    = (const float*)d_in[7];
    const float* bd    = (const float*)d_in[8];
    const float* alpha = (const float*)d_in[9];
    float* out = (float*)d_out;

    // ws: featq8 bf16 [4][4096][8] 256KB | featk8 256KB | featdf frag 2MB
    unsigned short* featq8 = (unsigned short*)d_ws;
    unsigned short* featk8 = featq8 + (size_t)BATCH*NSP*8;
    unsigned short* featdf = featk8 + (size_t)BATCH*NSP*8;

    proj_kernel<<<dim3(NSP/64, 2, BATCH), 256, 0, stream>>>(
        map1, map2, fm, wb, bb, wc, bc, wd, bd, featq8, featk8, featdf);
    attn_kernel<<<dim3(NSP/16, BATCH), 256, 0, stream>>>(
        featq8, featk8, featdf, fm, alpha, out);
}